// Round 3
// baseline (2883.882 us; speedup 1.0000x reference)
//
#include <hip/hip_runtime.h>
#include <cstdint>

// GCN: two-level LDS-staged edge partition (bucket = dst>>7, 128 nodes/bucket),
// then per-bucket LDS-accumulated aggregation. dinv folded into GEMM epilogue.

constexpr int CHUNK = 8192;  // edges per partition block

// ---- P2: per-chunk bucket sort into pairs1 (chunk-grouped, packed 4B) ----
__global__ __launch_bounds__(256) void p2_localsort(
        const int* __restrict__ esrc, const int* __restrict__ edst, int E,
        unsigned* __restrict__ pairs1, int* __restrict__ cntMat,
        int* __restrict__ startMat, int NBK) {
    __shared__ int hist[1024];
    __shared__ int wsum[256];
    __shared__ unsigned lp[CHUNK];        // 32 KB
    const int t = threadIdx.x, blk = blockIdx.x;
    const int base = blk * CHUNK;
    const int cnt = min(CHUNK, E - base);
    for (int i = t; i < 1024; i += 256) hist[i] = 0;
    __syncthreads();
    for (int i = t; i < cnt; i += 256) atomicAdd(&hist[edst[base + i] >> 7], 1);
    __syncthreads();
    int h0 = hist[4*t], h1 = hist[4*t+1], h2 = hist[4*t+2], h3 = hist[4*t+3];
    int s = h0 + h1 + h2 + h3;
    wsum[t] = s; __syncthreads();
    #pragma unroll
    for (int o = 1; o < 256; o <<= 1) {
        int x = (t >= o) ? wsum[t - o] : 0;
        __syncthreads(); wsum[t] += x; __syncthreads();
    }
    int run = wsum[t] - s;                 // exclusive over thread groups
    int e0 = run, e1 = run + h0, e2 = e1 + h1, e3 = e2 + h2;
    hist[4*t] = e0; hist[4*t+1] = e1; hist[4*t+2] = e2; hist[4*t+3] = e3;
    if (4*t     < NBK) { cntMat[(size_t)blk*NBK + 4*t]     = h0; startMat[(size_t)blk*NBK + 4*t]     = e0; }
    if (4*t + 1 < NBK) { cntMat[(size_t)blk*NBK + 4*t + 1] = h1; startMat[(size_t)blk*NBK + 4*t + 1] = e1; }
    if (4*t + 2 < NBK) { cntMat[(size_t)blk*NBK + 4*t + 2] = h2; startMat[(size_t)blk*NBK + 4*t + 2] = e2; }
    if (4*t + 3 < NBK) { cntMat[(size_t)blk*NBK + 4*t + 3] = h3; startMat[(size_t)blk*NBK + 4*t + 3] = e3; }
    __syncthreads();
    for (int i = t; i < cnt; i += 256) {
        int d = edst[base + i];
        int pos = atomicAdd(&hist[d >> 7], 1);
        lp[pos] = ((unsigned)(d & 127) << 17) | (unsigned)esrc[base + i];
    }
    __syncthreads();
    for (int i = t; i < cnt; i += 256) pairs1[base + i] = lp[i];  // coalesced
}

// ---- P3: column-wise exclusive scan of cntMat over chunks; totals -> TB ----
__global__ __launch_bounds__(256) void p3_colscan(int* __restrict__ cntMat,
        int* __restrict__ TB, int nchunks, int NBK) {
    __shared__ int buf[512];
    const int t = threadIdx.x, b = blockIdx.x;
    int v0 = (t < nchunks) ? cntMat[(size_t)t*NBK + b] : 0;
    int v1 = (t + 256 < nchunks) ? cntMat[(size_t)(t + 256)*NBK + b] : 0;
    buf[t] = v0; buf[t + 256] = v1; __syncthreads();
    #pragma unroll
    for (int o = 1; o < 512; o <<= 1) {
        int x0 = (t >= o) ? buf[t - o] : 0;
        int x1 = (t + 256 >= o) ? buf[t + 256 - o] : 0;
        __syncthreads(); buf[t] += x0; buf[t + 256] += x1; __syncthreads();
    }
    if (t < nchunks) cntMat[(size_t)t*NBK + b] = buf[t] - v0;          // cumBefore
    if (t + 256 < nchunks) cntMat[(size_t)(t + 256)*NBK + b] = buf[t + 256] - v1;
    if (t == 0) TB[b] = buf[511];
}

// ---- P4: exclusive scan of TB -> bucketBase ----
__global__ __launch_bounds__(256) void p4_scan(const int* __restrict__ TB,
        int* __restrict__ bucketBase, int NBK, int E) {
    __shared__ int buf[1024];
    __shared__ int wsum[256];
    const int t = threadIdx.x;
    for (int i = t; i < 1024; i += 256) buf[i] = (i < NBK) ? TB[i] : 0;
    __syncthreads();
    int h0 = buf[4*t], h1 = buf[4*t+1], h2 = buf[4*t+2], h3 = buf[4*t+3];
    int s = h0 + h1 + h2 + h3;
    wsum[t] = s; __syncthreads();
    #pragma unroll
    for (int o = 1; o < 256; o <<= 1) {
        int x = (t >= o) ? wsum[t - o] : 0;
        __syncthreads(); wsum[t] += x; __syncthreads();
    }
    int run = wsum[t] - s;
    int e0 = run, e1 = run + h0, e2 = e1 + h1, e3 = e2 + h2;
    if (4*t     < NBK) bucketBase[4*t]     = e0;
    if (4*t + 1 < NBK) bucketBase[4*t + 1] = e1;
    if (4*t + 2 < NBK) bucketBase[4*t + 2] = e2;
    if (4*t + 3 < NBK) bucketBase[4*t + 3] = e3;
    if (t == 0) bucketBase[NBK] = E;
}

// ---- P5: chunk-grouped -> bucket-contiguous pairs2 ----
__global__ __launch_bounds__(256) void p5_gather(const unsigned* __restrict__ pairs1,
        unsigned* __restrict__ pairs2, const int* __restrict__ cumMat,
        const int* __restrict__ startMat, const int* __restrict__ bucketBase,
        int E, int NBK) {
    __shared__ int sstart[1024];
    __shared__ int sdest[1024];
    const int t = threadIdx.x, blk = blockIdx.x;
    const int base = blk * CHUNK;
    const int cnt = min(CHUNK, E - base);
    for (int b = t; b < NBK; b += 256) {
        int st = startMat[(size_t)blk*NBK + b];
        sstart[b] = st;
        sdest[b] = bucketBase[b] + cumMat[(size_t)blk*NBK + b] - st;
    }
    __syncthreads();
    for (int i = t; i < cnt; i += 256) {
        unsigned pk = pairs1[base + i];
        int lo = 0, hi = NBK - 1;          // largest b with sstart[b] <= i
        while (lo < hi) {
            int mid = (lo + hi + 1) >> 1;
            if (sstart[mid] <= i) lo = mid; else hi = mid - 1;
        }
        pairs2[sdest[lo] + i] = pk;
    }
}

// ---- P6: per-bucket degree histogram -> dinv ----
__global__ __launch_bounds__(256) void p6_deg(const unsigned* __restrict__ pairs2,
        const int* __restrict__ bucketBase, float* __restrict__ dinv, int N) {
    __shared__ int cnt[128];
    const int t = threadIdx.x, b = blockIdx.x;
    if (t < 128) cnt[t] = 0;
    __syncthreads();
    const int beg = bucketBase[b], end = bucketBase[b + 1];
    for (int i = beg + t; i < end; i += 256)
        atomicAdd(&cnt[pairs2[i] >> 17], 1);
    __syncthreads();
    if (t < 128) {
        int d = b * 128 + t;
        if (d < N) dinv[d] = rsqrtf((float)cnt[t] + 1.0f);  // +1 self-loop
    }
}

// ---- GEMM: G[row,:] = (X[row,:] @ W) * dinv[row], 64 cols ----
template<int K>
__global__ __launch_bounds__(256) void k_gemm(const float* __restrict__ X,
        const float* __restrict__ Wm, const float* __restrict__ dinv,
        float* __restrict__ G, int nrows) {
    constexpr int BK = 32;
    constexpr int NCH = K / BK;
    constexpr int PITCH = 132;
    __shared__ float Xs[BK * PITCH];
    __shared__ float Ws[BK * 64];
    const int t = threadIdx.x;
    const int cg = t & 7;
    const int rg = t >> 3;
    const int brow = blockIdx.x * 128;

    float acc[4][8];
    #pragma unroll
    for (int r = 0; r < 4; ++r)
        #pragma unroll
        for (int c = 0; c < 8; ++c) acc[r][c] = 0.f;

    for (int ch = 0; ch < NCH; ++ch) {
        if (ch) __syncthreads();
        #pragma unroll
        for (int i = 0; i < 4; ++i) {
            int f = t + i * 256;
            int r = f >> 3, c4 = f & 7;
            int gr = brow + r;
            float4 v = make_float4(0.f, 0.f, 0.f, 0.f);
            if (gr < nrows)
                v = *(const float4*)(X + (size_t)gr * K + ch * BK + c4 * 4);
            Xs[(c4 * 4 + 0) * PITCH + r] = v.x;
            Xs[(c4 * 4 + 1) * PITCH + r] = v.y;
            Xs[(c4 * 4 + 2) * PITCH + r] = v.z;
            Xs[(c4 * 4 + 3) * PITCH + r] = v.w;
        }
        #pragma unroll
        for (int i = 0; i < 2; ++i) {
            int f = t + i * 256;
            int k = f >> 4, c4 = f & 15;
            *(float4*)(Ws + k * 64 + c4 * 4) =
                *(const float4*)(Wm + (size_t)(ch * BK + k) * 64 + c4 * 4);
        }
        __syncthreads();

        #pragma unroll
        for (int k = 0; k < BK; ++k) {
            float4 xa = *(const float4*)(Xs + k * PITCH + rg * 4);
            float4 w0 = *(const float4*)(Ws + k * 64 + cg * 8);
            float4 w1 = *(const float4*)(Ws + k * 64 + cg * 8 + 4);
#define FMA_ROW(r, xv) \
            acc[r][0] += (xv) * w0.x; acc[r][1] += (xv) * w0.y; \
            acc[r][2] += (xv) * w0.z; acc[r][3] += (xv) * w0.w; \
            acc[r][4] += (xv) * w1.x; acc[r][5] += (xv) * w1.y; \
            acc[r][6] += (xv) * w1.z; acc[r][7] += (xv) * w1.w;
            FMA_ROW(0, xa.x) FMA_ROW(1, xa.y) FMA_ROW(2, xa.z) FMA_ROW(3, xa.w)
#undef FMA_ROW
        }
    }
    #pragma unroll
    for (int r = 0; r < 4; ++r) {
        int gr = brow + rg * 4 + r;
        if (gr < nrows) {
            float dv = dinv[gr];
            float4 o0 = make_float4(acc[r][0] * dv, acc[r][1] * dv,
                                    acc[r][2] * dv, acc[r][3] * dv);
            float4 o1 = make_float4(acc[r][4] * dv, acc[r][5] * dv,
                                    acc[r][6] * dv, acc[r][7] * dv);
            *(float4*)(G + (size_t)gr * 64 + cg * 8)     = o0;
            *(float4*)(G + (size_t)gr * 64 + cg * 8 + 4) = o1;
        }
    }
}

// ---- Aggregate per bucket: LDS acc[128][64]; H = relu(dinv*(sum+self)+b) ----
__global__ __launch_bounds__(256) void k_aggB(const float* __restrict__ G,
        const unsigned* __restrict__ pairs2, const int* __restrict__ bucketBase,
        const float* __restrict__ dinv, const float* __restrict__ bias,
        float* __restrict__ H, int N) {
    __shared__ float sacc[128 * 64];       // 32 KB
    const int t = threadIdx.x, b = blockIdx.x;
    for (int i = t; i < 2048; i += 256)
        ((float4*)sacc)[i] = make_float4(0.f, 0.f, 0.f, 0.f);
    __syncthreads();
    const int l = t & 63;                  // lane = feature
    const int w = __builtin_amdgcn_readfirstlane(t >> 6);  // wave id (uniform)
    const int beg = bucketBase[b], end = bucketBase[b + 1];
    int e = beg + w;                       // waves interleave stride 4
    for (; e + 12 < end; e += 16) {
        unsigned p0 = pairs2[e], p1 = pairs2[e + 4];
        unsigned p2 = pairs2[e + 8], p3 = pairs2[e + 12];
        float v0 = G[(size_t)(p0 & 0x1FFFFu) * 64 + l];
        float v1 = G[(size_t)(p1 & 0x1FFFFu) * 64 + l];
        float v2 = G[(size_t)(p2 & 0x1FFFFu) * 64 + l];
        float v3 = G[(size_t)(p3 & 0x1FFFFu) * 64 + l];
        atomicAdd(&sacc[(p0 >> 17) * 64 + l], v0);
        atomicAdd(&sacc[(p1 >> 17) * 64 + l], v1);
        atomicAdd(&sacc[(p2 >> 17) * 64 + l], v2);
        atomicAdd(&sacc[(p3 >> 17) * 64 + l], v3);
    }
    for (; e < end; e += 4) {
        unsigned p = pairs2[e];
        float v = G[(size_t)(p & 0x1FFFFu) * 64 + l];
        atomicAdd(&sacc[(p >> 17) * 64 + l], v);
    }
    __syncthreads();
    const float4* G4 = (const float4*)G;
    const float4* B4 = (const float4*)bias;
    float4* H4 = (float4*)H;
    for (int i = t; i < 2048; i += 256) {
        int node = i >> 4, p = i & 15;
        int d = b * 128 + node;
        if (d < N) {
            float4 a = ((const float4*)sacc)[i];
            float4 self = G4[(size_t)d * 16 + p];
            float dv = dinv[d];
            float4 bb = B4[p];
            float4 o;
            o.x = fmaxf((a.x + self.x) * dv + bb.x, 0.f);
            o.y = fmaxf((a.y + self.y) * dv + bb.y, 0.f);
            o.z = fmaxf((a.z + self.z) * dv + bb.z, 0.f);
            o.w = fmaxf((a.w + self.w) * dv + bb.w, 0.f);
            H4[(size_t)d * 16 + p] = o;
        }
    }
}

// ---- Head: out[row,:] = log_softmax(H[row,:] @ W3 + b3), OUT=40 ----
__global__ __launch_bounds__(256) void k_final(const float* __restrict__ H,
        const float* __restrict__ W3, const float* __restrict__ b3,
        float* __restrict__ out, int nrows) {
    __shared__ float wl[64 * 40];
    __shared__ float bl[40];
    int t = threadIdx.x;
    for (int i = t; i < 640; i += 256)
        ((float4*)wl)[i] = ((const float4*)W3)[i];
    if (t < 40) bl[t] = b3[t];
    __syncthreads();
    for (int row = blockIdx.x * 256 + t; row < nrows; row += gridDim.x * 256) {
        float acc[40];
        #pragma unroll
        for (int j = 0; j < 40; ++j) acc[j] = bl[j];
        const float4* hr = (const float4*)(H + (size_t)row * 64);
        #pragma unroll
        for (int k4 = 0; k4 < 16; ++k4) {
            float4 h4 = hr[k4];
            float hv[4] = {h4.x, h4.y, h4.z, h4.w};
            #pragma unroll
            for (int c = 0; c < 4; ++c) {
                const float4* wr = (const float4*)(wl + (k4 * 4 + c) * 40);
                #pragma unroll
                for (int j4 = 0; j4 < 10; ++j4) {
                    float4 wv = wr[j4];
                    acc[j4 * 4 + 0] += hv[c] * wv.x;
                    acc[j4 * 4 + 1] += hv[c] * wv.y;
                    acc[j4 * 4 + 2] += hv[c] * wv.z;
                    acc[j4 * 4 + 3] += hv[c] * wv.w;
                }
            }
        }
        float m = acc[0];
        #pragma unroll
        for (int j = 1; j < 40; ++j) m = fmaxf(m, acc[j]);
        float s = 0.f;
        #pragma unroll
        for (int j = 0; j < 40; ++j) s += expf(acc[j] - m);
        float lse = m + logf(s);
        float* orow = out + (size_t)row * 40;
        #pragma unroll
        for (int j4 = 0; j4 < 10; ++j4) {
            ((float4*)orow)[j4] = make_float4(acc[j4 * 4 + 0] - lse, acc[j4 * 4 + 1] - lse,
                                              acc[j4 * 4 + 2] - lse, acc[j4 * 4 + 3] - lse);
        }
    }
}

extern "C" void kernel_launch(void* const* d_in, const int* in_sizes, int n_in,
                              void* d_out, int out_size, void* d_ws, size_t ws_size,
                              hipStream_t stream) {
    const float* x  = (const float*)d_in[0];
    const int*   ei = (const int*)d_in[1];     // [2][E]: row0=src, row1=dst
    const float* W1 = (const float*)d_in[2];
    const float* b1 = (const float*)d_in[3];
    const float* W2 = (const float*)d_in[4];
    const float* b2 = (const float*)d_in[5];
    const float* W3 = (const float*)d_in[6];
    const float* b3 = (const float*)d_in[7];
    float* out = (float*)d_out;

    const int HID = in_sizes[3];            // 64
    const int IND = in_sizes[2] / HID;      // 256
    const int N   = in_sizes[0] / IND;      // 100000
    const int E   = in_sizes[1] / 2;        // 3200000
    (void)HID; (void)n_in; (void)out_size; (void)ws_size;

    const int NBK     = (N + 127) >> 7;     // 782 buckets of 128 nodes
    const int nchunks = (E + CHUNK - 1) / CHUNK;  // 391

    char* ws = (char*)d_ws;
    size_t off = 0;
    auto alloc = [&](size_t bytes) -> char* {
        char* p = ws + off;
        off = (off + bytes + 255) & ~(size_t)255;
        return p;
    };
    int*      cntMat     = (int*)     alloc((size_t)nchunks * NBK * 4);
    int*      startMat   = (int*)     alloc((size_t)nchunks * NBK * 4);
    int*      TB         = (int*)     alloc((size_t)NBK * 4);
    int*      bucketBase = (int*)     alloc(((size_t)NBK + 1) * 4);
    float*    dinv       = (float*)   alloc((size_t)N * 4);
    unsigned* pairs2     = (unsigned*)alloc((size_t)E * 4);
    float*    g          = (float*)   alloc((size_t)N * 64 * 4);
    float*    h          = (float*)   alloc((size_t)N * 64 * 4);
    unsigned* pairs1     = (unsigned*)g;    // overlay: dead before gemm1 writes g

    const int* esrc = ei;
    const int* edst = ei + E;
    const int gM = (N + 127) / 128;
    const int gN = (N + 255) / 256;

    p2_localsort<<<nchunks, 256, 0, stream>>>(esrc, edst, E, pairs1, cntMat, startMat, NBK);
    p3_colscan  <<<NBK, 256, 0, stream>>>(cntMat, TB, nchunks, NBK);
    p4_scan     <<<1, 256, 0, stream>>>(TB, bucketBase, NBK, E);
    p5_gather   <<<nchunks, 256, 0, stream>>>(pairs1, pairs2, cntMat, startMat, bucketBase, E, NBK);
    p6_deg      <<<NBK, 256, 0, stream>>>(pairs2, bucketBase, dinv, N);

    k_gemm<256> <<<gM, 256, 0, stream>>>(x, W1, dinv, g, N);
    k_aggB      <<<NBK, 256, 0, stream>>>(g, pairs2, bucketBase, dinv, b1, h, N);
    k_gemm<64>  <<<gM, 256, 0, stream>>>(h, W2, dinv, g, N);
    k_aggB      <<<NBK, 256, 0, stream>>>(g, pairs2, bucketBase, dinv, b2, h, N);
    k_final     <<<gN, 256, 0, stream>>>(h, W3, b3, out, N);
}

// Round 4
// 429.246 us; speedup vs baseline: 6.7185x; 6.7185x over previous
//
#include <hip/hip_runtime.h>
#include <cstdint>

// GCN: chunk-local bucket partition -> per-bucket LDS counting-sort to CSR ->
// register-accumulating gather aggregation. dinv folded into GEMM epilogue.

constexpr int CHUNK = 8192;   // edges per partition chunk
constexpr int BKCAP = 8192;   // max edges per 128-node bucket (mean 4096, std 64)

// ---- P2: per-chunk bucket sort into pairs1 (chunk-grouped, packed 4B) ----
__global__ __launch_bounds__(256) void p2_localsort(
        const int* __restrict__ esrc, const int* __restrict__ edst, int E,
        unsigned* __restrict__ pairs1, int* __restrict__ cntMat,
        int* __restrict__ startMat, int NBK) {
    __shared__ int hist[1024];
    __shared__ int wsum[256];
    __shared__ unsigned lp[CHUNK];        // 32 KB
    const int t = threadIdx.x, blk = blockIdx.x;
    const int base = blk * CHUNK;
    const int cnt = min(CHUNK, E - base);
    for (int i = t; i < 1024; i += 256) hist[i] = 0;
    __syncthreads();
    for (int i = t; i < cnt; i += 256) atomicAdd(&hist[edst[base + i] >> 7], 1);
    __syncthreads();
    int h0 = hist[4*t], h1 = hist[4*t+1], h2 = hist[4*t+2], h3 = hist[4*t+3];
    int s = h0 + h1 + h2 + h3;
    wsum[t] = s; __syncthreads();
    #pragma unroll
    for (int o = 1; o < 256; o <<= 1) {
        int x = (t >= o) ? wsum[t - o] : 0;
        __syncthreads(); wsum[t] += x; __syncthreads();
    }
    int run = wsum[t] - s;
    int e0 = run, e1 = run + h0, e2 = e1 + h1, e3 = e2 + h2;
    hist[4*t] = e0; hist[4*t+1] = e1; hist[4*t+2] = e2; hist[4*t+3] = e3;
    if (4*t     < NBK) { cntMat[(size_t)blk*NBK + 4*t]     = h0; startMat[(size_t)blk*NBK + 4*t]     = e0; }
    if (4*t + 1 < NBK) { cntMat[(size_t)blk*NBK + 4*t + 1] = h1; startMat[(size_t)blk*NBK + 4*t + 1] = e1; }
    if (4*t + 2 < NBK) { cntMat[(size_t)blk*NBK + 4*t + 2] = h2; startMat[(size_t)blk*NBK + 4*t + 2] = e2; }
    if (4*t + 3 < NBK) { cntMat[(size_t)blk*NBK + 4*t + 3] = h3; startMat[(size_t)blk*NBK + 4*t + 3] = e3; }
    __syncthreads();
    for (int i = t; i < cnt; i += 256) {
        int d = edst[base + i];
        int pos = atomicAdd(&hist[d >> 7], 1);
        lp[pos] = ((unsigned)(d & 127) << 17) | (unsigned)esrc[base + i];
    }
    __syncthreads();
    for (int i = t; i < cnt; i += 256) pairs1[base + i] = lp[i];  // coalesced
}

// ---- P3: column-wise exclusive scan of cntMat over chunks; totals -> TB ----
__global__ __launch_bounds__(256) void p3_colscan(int* __restrict__ cntMat,
        int* __restrict__ TB, int nchunks, int NBK) {
    __shared__ int buf[512];
    const int t = threadIdx.x, b = blockIdx.x;
    int v0 = (t < nchunks) ? cntMat[(size_t)t*NBK + b] : 0;
    int v1 = (t + 256 < nchunks) ? cntMat[(size_t)(t + 256)*NBK + b] : 0;
    buf[t] = v0; buf[t + 256] = v1; __syncthreads();
    #pragma unroll
    for (int o = 1; o < 512; o <<= 1) {
        int x0 = (t >= o) ? buf[t - o] : 0;
        int x1 = (t + 256 >= o) ? buf[t + 256 - o] : 0;
        __syncthreads(); buf[t] += x0; buf[t + 256] += x1; __syncthreads();
    }
    if (t < nchunks) cntMat[(size_t)t*NBK + b] = buf[t] - v0;          // cumBefore
    if (t + 256 < nchunks) cntMat[(size_t)(t + 256)*NBK + b] = buf[t + 256] - v1;
    if (t == 0) TB[b] = buf[511];
}

// ---- P4: exclusive scan of TB -> bucketBase ----
__global__ __launch_bounds__(256) void p4_scan(const int* __restrict__ TB,
        int* __restrict__ bucketBase, int NBK, int E) {
    __shared__ int buf[1024];
    __shared__ int wsum[256];
    const int t = threadIdx.x;
    for (int i = t; i < 1024; i += 256) buf[i] = (i < NBK) ? TB[i] : 0;
    __syncthreads();
    int h0 = buf[4*t], h1 = buf[4*t+1], h2 = buf[4*t+2], h3 = buf[4*t+3];
    int s = h0 + h1 + h2 + h3;
    wsum[t] = s; __syncthreads();
    #pragma unroll
    for (int o = 1; o < 256; o <<= 1) {
        int x = (t >= o) ? wsum[t - o] : 0;
        __syncthreads(); wsum[t] += x; __syncthreads();
    }
    int run = wsum[t] - s;
    int e0 = run, e1 = run + h0, e2 = e1 + h1, e3 = e2 + h2;
    if (4*t     < NBK) bucketBase[4*t]     = e0;
    if (4*t + 1 < NBK) bucketBase[4*t + 1] = e1;
    if (4*t + 2 < NBK) bucketBase[4*t + 2] = e2;
    if (4*t + 3 < NBK) bucketBase[4*t + 3] = e3;
    if (t == 0) bucketBase[NBK] = E;
}

// ---- P6: per-bucket gather from pairs1 + LDS counting-sort by node ->
//      csrc (CSR order), rofs[node], dinv[node]. One block per bucket. ----
__global__ __launch_bounds__(256) void p6_sortcsr(
        const unsigned* __restrict__ pairs1, const int* __restrict__ cumMat,
        const int* __restrict__ startMat, const int* __restrict__ TB,
        const int* __restrict__ bucketBase, int nchunks, int NBK,
        int* __restrict__ csrc, int* __restrict__ rofs,
        float* __restrict__ dinv, int N, int E) {
    __shared__ unsigned lp[BKCAP];        // 32 KB
    __shared__ int ccum[512];             // column of cumMat (+ sentinel)
    __shared__ int cstart[512];
    __shared__ int hist[128];
    __shared__ int sc[128];
    __shared__ int foffs[128];
    const int t = threadIdx.x, b = blockIdx.x;
    const int total0 = TB[b];
    const int total = min(total0, BKCAP);
    const int base = bucketBase[b];
    for (int i = t; i < nchunks; i += 256) {
        ccum[i]   = cumMat[(size_t)i * NBK + b];
        cstart[i] = startMat[(size_t)i * NBK + b];
    }
    if (t < 128) hist[t] = 0;
    if (t == 0) ccum[nchunks] = total0;
    __syncthreads();
    // gather bucket edges (chunk-major order) + histogram nodes
    for (int i = t; i < total; i += 256) {
        int lo = 0, hi = nchunks - 1;     // largest c with ccum[c] <= i
        while (lo < hi) {
            int mid = (lo + hi + 1) >> 1;
            if (ccum[mid] <= i) lo = mid; else hi = mid - 1;
        }
        unsigned v = pairs1[(size_t)lo * CHUNK + cstart[lo] + (i - ccum[lo])];
        lp[i] = v;
        atomicAdd(&hist[v >> 17], 1);
    }
    __syncthreads();
    // exclusive scan of hist[128]
    if (t < 128) sc[t] = hist[t];
    __syncthreads();
    #pragma unroll
    for (int o = 1; o < 128; o <<= 1) {
        int x = (t >= o && t < 128) ? sc[t - o] : 0;
        __syncthreads();
        if (t < 128) sc[t] += x;
        __syncthreads();
    }
    if (t < 128) {
        int excl = sc[t] - hist[t];
        foffs[t] = excl;
        int node = b * 128 + t;
        if (node < N) {
            rofs[node] = base + excl;
            dinv[node] = rsqrtf((float)hist[t] + 1.0f);   // +1 self-loop
        }
    }
    if (b == 0 && t == 255) rofs[N] = E;
    __syncthreads();
    // scatter src ids to CSR positions (16KB global window -> L2-resident)
    for (int i = t; i < total; i += 256) {
        unsigned v = lp[i];
        int pos = atomicAdd(&foffs[v >> 17], 1);
        csrc[base + pos] = (int)(v & 0x1FFFFu);
    }
}

// ---- GEMM: G[row,:] = (X[row,:] @ W) * dinv[row], 64 cols ----
template<int K>
__global__ __launch_bounds__(256) void k_gemm(const float* __restrict__ X,
        const float* __restrict__ Wm, const float* __restrict__ dinv,
        float* __restrict__ G, int nrows) {
    constexpr int BK = 32;
    constexpr int NCH = K / BK;
    constexpr int PITCH = 132;
    __shared__ float Xs[BK * PITCH];
    __shared__ float Ws[BK * 64];
    const int t = threadIdx.x;
    const int cg = t & 7;
    const int rg = t >> 3;
    const int brow = blockIdx.x * 128;

    float acc[4][8];
    #pragma unroll
    for (int r = 0; r < 4; ++r)
        #pragma unroll
        for (int c = 0; c < 8; ++c) acc[r][c] = 0.f;

    for (int ch = 0; ch < NCH; ++ch) {
        if (ch) __syncthreads();
        #pragma unroll
        for (int i = 0; i < 4; ++i) {
            int f = t + i * 256;
            int r = f >> 3, c4 = f & 7;
            int gr = brow + r;
            float4 v = make_float4(0.f, 0.f, 0.f, 0.f);
            if (gr < nrows)
                v = *(const float4*)(X + (size_t)gr * K + ch * BK + c4 * 4);
            Xs[(c4 * 4 + 0) * PITCH + r] = v.x;
            Xs[(c4 * 4 + 1) * PITCH + r] = v.y;
            Xs[(c4 * 4 + 2) * PITCH + r] = v.z;
            Xs[(c4 * 4 + 3) * PITCH + r] = v.w;
        }
        #pragma unroll
        for (int i = 0; i < 2; ++i) {
            int f = t + i * 256;
            int k = f >> 4, c4 = f & 15;
            *(float4*)(Ws + k * 64 + c4 * 4) =
                *(const float4*)(Wm + (size_t)(ch * BK + k) * 64 + c4 * 4);
        }
        __syncthreads();

        #pragma unroll
        for (int k = 0; k < BK; ++k) {
            float4 xa = *(const float4*)(Xs + k * PITCH + rg * 4);
            float4 w0 = *(const float4*)(Ws + k * 64 + cg * 8);
            float4 w1 = *(const float4*)(Ws + k * 64 + cg * 8 + 4);
#define FMA_ROW(r, xv) \
            acc[r][0] += (xv) * w0.x; acc[r][1] += (xv) * w0.y; \
            acc[r][2] += (xv) * w0.z; acc[r][3] += (xv) * w0.w; \
            acc[r][4] += (xv) * w1.x; acc[r][5] += (xv) * w1.y; \
            acc[r][6] += (xv) * w1.z; acc[r][7] += (xv) * w1.w;
            FMA_ROW(0, xa.x) FMA_ROW(1, xa.y) FMA_ROW(2, xa.z) FMA_ROW(3, xa.w)
#undef FMA_ROW
        }
    }
    #pragma unroll
    for (int r = 0; r < 4; ++r) {
        int gr = brow + rg * 4 + r;
        if (gr < nrows) {
            float dv = dinv[gr];
            float4 o0 = make_float4(acc[r][0] * dv, acc[r][1] * dv,
                                    acc[r][2] * dv, acc[r][3] * dv);
            float4 o1 = make_float4(acc[r][4] * dv, acc[r][5] * dv,
                                    acc[r][6] * dv, acc[r][7] * dv);
            *(float4*)(G + (size_t)gr * 64 + cg * 8)     = o0;
            *(float4*)(G + (size_t)gr * 64 + cg * 8 + 4) = o1;
        }
    }
}

// ---- Aggregate: H[d,:] = relu(dinv[d]*(G[d,:] + sum_{e in CSR[d]} G[src_e,:]) + b)
// One wave per node; quarter-wave (16 lanes x float4) per edge; register acc;
// no LDS -> 32 waves/CU, latency hidden by TLP.
__global__ __launch_bounds__(256) void k_agg(const float* __restrict__ G,
        const int* __restrict__ rofs, const int* __restrict__ csrc,
        const float* __restrict__ dinv, const float* __restrict__ bias,
        float* __restrict__ H, int nrows) {
    const int l = threadIdx.x & 63;
    const int q = l >> 4;
    const int p = l & 15;
    const int d = blockIdx.x * 4 + (threadIdx.x >> 6);
    if (d >= nrows) return;                // wave-uniform
    const int beg = rofs[d], end = rofs[d + 1];
    const float4* __restrict__ G4 = (const float4*)G;
    float4 acc = make_float4(0.f, 0.f, 0.f, 0.f);

    for (int e = beg; e < end; e += 64) {
        int nrem = end - e; if (nrem > 64) nrem = 64;
        int idx = (l < nrem) ? csrc[e + l] : 0;
        const int full = nrem >> 2;
        int kk = 0;
        for (; kk + 4 <= full; kk += 4) {
            int s0 = __shfl(idx, (kk + 0) * 4 + q);
            int s1 = __shfl(idx, (kk + 1) * 4 + q);
            int s2 = __shfl(idx, (kk + 2) * 4 + q);
            int s3 = __shfl(idx, (kk + 3) * 4 + q);
            float4 v0 = G4[s0 * 16 + p];
            float4 v1 = G4[s1 * 16 + p];
            float4 v2 = G4[s2 * 16 + p];
            float4 v3 = G4[s3 * 16 + p];
            acc.x += v0.x; acc.y += v0.y; acc.z += v0.z; acc.w += v0.w;
            acc.x += v1.x; acc.y += v1.y; acc.z += v1.z; acc.w += v1.w;
            acc.x += v2.x; acc.y += v2.y; acc.z += v2.z; acc.w += v2.w;
            acc.x += v3.x; acc.y += v3.y; acc.z += v3.z; acc.w += v3.w;
        }
        for (; kk < full; ++kk) {
            int s = __shfl(idx, kk * 4 + q);
            float4 v = G4[s * 16 + p];
            acc.x += v.x; acc.y += v.y; acc.z += v.z; acc.w += v.w;
        }
        int tq = full * 4 + q;
        if (tq < nrem) {
            int s = __shfl(idx, tq);
            float4 v = G4[s * 16 + p];
            acc.x += v.x; acc.y += v.y; acc.z += v.z; acc.w += v.w;
        }
    }
    #pragma unroll
    for (int off = 16; off <= 32; off <<= 1) {
        acc.x += __shfl_xor(acc.x, off);
        acc.y += __shfl_xor(acc.y, off);
        acc.z += __shfl_xor(acc.z, off);
        acc.w += __shfl_xor(acc.w, off);
    }
    if (q == 0) {
        float4 self = G4[d * 16 + p];
        float dv = dinv[d];
        float4 b4 = ((const float4*)bias)[p];
        float4 o;
        o.x = fmaxf((acc.x + self.x) * dv + b4.x, 0.f);
        o.y = fmaxf((acc.y + self.y) * dv + b4.y, 0.f);
        o.z = fmaxf((acc.z + self.z) * dv + b4.z, 0.f);
        o.w = fmaxf((acc.w + self.w) * dv + b4.w, 0.f);
        ((float4*)H)[d * 16 + p] = o;
    }
}

// ---- Head: out[row,:] = log_softmax(H[row,:] @ W3 + b3), OUT=40 ----
__global__ __launch_bounds__(256) void k_final(const float* __restrict__ H,
        const float* __restrict__ W3, const float* __restrict__ b3,
        float* __restrict__ out, int nrows) {
    __shared__ float wl[64 * 40];
    __shared__ float bl[40];
    int t = threadIdx.x;
    for (int i = t; i < 640; i += 256)
        ((float4*)wl)[i] = ((const float4*)W3)[i];
    if (t < 40) bl[t] = b3[t];
    __syncthreads();
    for (int row = blockIdx.x * 256 + t; row < nrows; row += gridDim.x * 256) {
        float acc[40];
        #pragma unroll
        for (int j = 0; j < 40; ++j) acc[j] = bl[j];
        const float4* hr = (const float4*)(H + (size_t)row * 64);
        #pragma unroll
        for (int k4 = 0; k4 < 16; ++k4) {
            float4 h4 = hr[k4];
            float hv[4] = {h4.x, h4.y, h4.z, h4.w};
            #pragma unroll
            for (int c = 0; c < 4; ++c) {
                const float4* wr = (const float4*)(wl + (k4 * 4 + c) * 40);
                #pragma unroll
                for (int j4 = 0; j4 < 10; ++j4) {
                    float4 wv = wr[j4];
                    acc[j4 * 4 + 0] += hv[c] * wv.x;
                    acc[j4 * 4 + 1] += hv[c] * wv.y;
                    acc[j4 * 4 + 2] += hv[c] * wv.z;
                    acc[j4 * 4 + 3] += hv[c] * wv.w;
                }
            }
        }
        float m = acc[0];
        #pragma unroll
        for (int j = 1; j < 40; ++j) m = fmaxf(m, acc[j]);
        float s = 0.f;
        #pragma unroll
        for (int j = 0; j < 40; ++j) s += expf(acc[j] - m);
        float lse = m + logf(s);
        float* orow = out + (size_t)row * 40;
        #pragma unroll
        for (int j4 = 0; j4 < 10; ++j4) {
            ((float4*)orow)[j4] = make_float4(acc[j4 * 4 + 0] - lse, acc[j4 * 4 + 1] - lse,
                                              acc[j4 * 4 + 2] - lse, acc[j4 * 4 + 3] - lse);
        }
    }
}

extern "C" void kernel_launch(void* const* d_in, const int* in_sizes, int n_in,
                              void* d_out, int out_size, void* d_ws, size_t ws_size,
                              hipStream_t stream) {
    const float* x  = (const float*)d_in[0];
    const int*   ei = (const int*)d_in[1];     // [2][E]: row0=src, row1=dst
    const float* W1 = (const float*)d_in[2];
    const float* b1 = (const float*)d_in[3];
    const float* W2 = (const float*)d_in[4];
    const float* b2 = (const float*)d_in[5];
    const float* W3 = (const float*)d_in[6];
    const float* b3 = (const float*)d_in[7];
    float* out = (float*)d_out;

    const int HID = in_sizes[3];            // 64
    const int IND = in_sizes[2] / HID;      // 256
    const int N   = in_sizes[0] / IND;      // 100000
    const int E   = in_sizes[1] / 2;        // 3200000
    (void)HID; (void)n_in; (void)out_size; (void)ws_size;

    const int NBK     = (N + 127) >> 7;             // 782
    const int nchunks = (E + CHUNK - 1) / CHUNK;    // 391

    char* ws = (char*)d_ws;
    size_t off = 0;
    auto alloc = [&](size_t bytes) -> char* {
        char* p = ws + off;
        off = (off + bytes + 255) & ~(size_t)255;
        return p;
    };
    int*      cntMat     = (int*)     alloc((size_t)nchunks * NBK * 4);
    int*      startMat   = (int*)     alloc((size_t)nchunks * NBK * 4);
    int*      TB         = (int*)     alloc((size_t)NBK * 4);
    int*      bucketBase = (int*)     alloc(((size_t)NBK + 1) * 4);
    float*    dinv       = (float*)   alloc((size_t)N * 4);
    int*      rofs       = (int*)     alloc(((size_t)N + 1) * 4);
    int*      csrc       = (int*)     alloc((size_t)E * 4);
    float*    g          = (float*)   alloc((size_t)N * 64 * 4);
    float*    h          = (float*)   alloc((size_t)N * 64 * 4);
    unsigned* pairs1     = (unsigned*)g;    // overlay: dead before gemm1 writes g

    const int* esrc = ei;
    const int* edst = ei + E;
    const int gM = (N + 127) / 128;
    const int gN = (N + 255) / 256;

    p2_localsort<<<nchunks, 256, 0, stream>>>(esrc, edst, E, pairs1, cntMat, startMat, NBK);
    p3_colscan  <<<NBK, 256, 0, stream>>>(cntMat, TB, nchunks, NBK);
    p4_scan     <<<1, 256, 0, stream>>>(TB, bucketBase, NBK, E);
    p6_sortcsr  <<<NBK, 256, 0, stream>>>(pairs1, cntMat, startMat, TB, bucketBase,
                                          nchunks, NBK, csrc, rofs, dinv, N, E);

    k_gemm<256> <<<gM, 256, 0, stream>>>(x, W1, dinv, g, N);
    k_agg       <<<(N + 3) / 4, 256, 0, stream>>>(g, rofs, csrc, dinv, b1, h, N);
    k_gemm<64>  <<<gM, 256, 0, stream>>>(h, W2, dinv, g, N);
    k_agg       <<<(N + 3) / 4, 256, 0, stream>>>(g, rofs, csrc, dinv, b2, h, N);
    k_final     <<<gN, 256, 0, stream>>>(h, W3, b3, out, N);
}

// Round 5
// 291.785 us; speedup vs baseline: 9.8836x; 1.4711x over previous
//
#include <hip/hip_runtime.h>
#include <hip/hip_fp16.h>
#include <cstdint>

// GCN: chunk-local bucket partition -> per-bucket LDS counting-sort to CSR ->
// register-accumulating gather aggregation over fp16 G (1 cache line per row).
// dinv folded into GEMM epilogue; fp32 accumulation everywhere.

constexpr int CHUNK = 8192;   // edges per partition chunk
constexpr int BKCAP = 8192;   // max edges per 128-node bucket (mean 4096)

// ---- P2: per-chunk bucket sort into pairs1 (chunk-grouped, packed 4B) ----
__global__ __launch_bounds__(256) void p2_localsort(
        const int* __restrict__ esrc, const int* __restrict__ edst, int E,
        unsigned* __restrict__ pairs1, int* __restrict__ cntMat,
        int* __restrict__ startMat, int NBK) {
    __shared__ int hist[1024];
    __shared__ int wsum[256];
    __shared__ unsigned lp[CHUNK];        // 32 KB
    const int t = threadIdx.x, blk = blockIdx.x;
    const int base = blk * CHUNK;
    const int cnt = min(CHUNK, E - base);
    for (int i = t; i < 1024; i += 256) hist[i] = 0;
    __syncthreads();
    for (int i = t; i < cnt; i += 256) atomicAdd(&hist[edst[base + i] >> 7], 1);
    __syncthreads();
    int h0 = hist[4*t], h1 = hist[4*t+1], h2 = hist[4*t+2], h3 = hist[4*t+3];
    int s = h0 + h1 + h2 + h3;
    wsum[t] = s; __syncthreads();
    #pragma unroll
    for (int o = 1; o < 256; o <<= 1) {
        int x = (t >= o) ? wsum[t - o] : 0;
        __syncthreads(); wsum[t] += x; __syncthreads();
    }
    int run = wsum[t] - s;
    int e0 = run, e1 = run + h0, e2 = e1 + h1, e3 = e2 + h2;
    hist[4*t] = e0; hist[4*t+1] = e1; hist[4*t+2] = e2; hist[4*t+3] = e3;
    if (4*t     < NBK) { cntMat[(size_t)blk*NBK + 4*t]     = h0; startMat[(size_t)blk*NBK + 4*t]     = e0; }
    if (4*t + 1 < NBK) { cntMat[(size_t)blk*NBK + 4*t + 1] = h1; startMat[(size_t)blk*NBK + 4*t + 1] = e1; }
    if (4*t + 2 < NBK) { cntMat[(size_t)blk*NBK + 4*t + 2] = h2; startMat[(size_t)blk*NBK + 4*t + 2] = e2; }
    if (4*t + 3 < NBK) { cntMat[(size_t)blk*NBK + 4*t + 3] = h3; startMat[(size_t)blk*NBK + 4*t + 3] = e3; }
    __syncthreads();
    for (int i = t; i < cnt; i += 256) {
        int d = edst[base + i];
        int pos = atomicAdd(&hist[d >> 7], 1);
        lp[pos] = ((unsigned)(d & 127) << 17) | (unsigned)esrc[base + i];
    }
    __syncthreads();
    for (int i = t; i < cnt; i += 256) pairs1[base + i] = lp[i];  // coalesced
}

// ---- P3: column-wise exclusive scan of cntMat over chunks; totals -> TB ----
__global__ __launch_bounds__(256) void p3_colscan(int* __restrict__ cntMat,
        int* __restrict__ TB, int nchunks, int NBK) {
    __shared__ int buf[512];
    const int t = threadIdx.x, b = blockIdx.x;
    int v0 = (t < nchunks) ? cntMat[(size_t)t*NBK + b] : 0;
    int v1 = (t + 256 < nchunks) ? cntMat[(size_t)(t + 256)*NBK + b] : 0;
    buf[t] = v0; buf[t + 256] = v1; __syncthreads();
    #pragma unroll
    for (int o = 1; o < 512; o <<= 1) {
        int x0 = (t >= o) ? buf[t - o] : 0;
        int x1 = (t + 256 >= o) ? buf[t + 256 - o] : 0;
        __syncthreads(); buf[t] += x0; buf[t + 256] += x1; __syncthreads();
    }
    if (t < nchunks) cntMat[(size_t)t*NBK + b] = buf[t] - v0;          // cumBefore
    if (t + 256 < nchunks) cntMat[(size_t)(t + 256)*NBK + b] = buf[t + 256] - v1;
    if (t == 0) TB[b] = buf[511];
}

// ---- P4: exclusive scan of TB -> bucketBase ----
__global__ __launch_bounds__(256) void p4_scan(const int* __restrict__ TB,
        int* __restrict__ bucketBase, int NBK, int E) {
    __shared__ int buf[1024];
    __shared__ int wsum[256];
    const int t = threadIdx.x;
    for (int i = t; i < 1024; i += 256) buf[i] = (i < NBK) ? TB[i] : 0;
    __syncthreads();
    int h0 = buf[4*t], h1 = buf[4*t+1], h2 = buf[4*t+2], h3 = buf[4*t+3];
    int s = h0 + h1 + h2 + h3;
    wsum[t] = s; __syncthreads();
    #pragma unroll
    for (int o = 1; o < 256; o <<= 1) {
        int x = (t >= o) ? wsum[t - o] : 0;
        __syncthreads(); wsum[t] += x; __syncthreads();
    }
    int run = wsum[t] - s;
    int e0 = run, e1 = run + h0, e2 = e1 + h1, e3 = e2 + h2;
    if (4*t     < NBK) bucketBase[4*t]     = e0;
    if (4*t + 1 < NBK) bucketBase[4*t + 1] = e1;
    if (4*t + 2 < NBK) bucketBase[4*t + 2] = e2;
    if (4*t + 3 < NBK) bucketBase[4*t + 3] = e3;
    if (t == 0) bucketBase[NBK] = E;
}

// ---- P6: per-bucket gather from pairs1 + LDS counting-sort by node ->
//      csrc (CSR order), rofs[node], dinv[node]. One block per bucket. ----
__global__ __launch_bounds__(256) void p6_sortcsr(
        const unsigned* __restrict__ pairs1, const int* __restrict__ cumMat,
        const int* __restrict__ startMat, const int* __restrict__ TB,
        const int* __restrict__ bucketBase, int nchunks, int NBK,
        int* __restrict__ csrc, int* __restrict__ rofs,
        float* __restrict__ dinv, int N, int E) {
    __shared__ unsigned lp[BKCAP];        // 32 KB
    __shared__ int ccum[512];
    __shared__ int cstart[512];
    __shared__ int hist[128];
    __shared__ int sc[128];
    __shared__ int foffs[128];
    const int t = threadIdx.x, b = blockIdx.x;
    const int total0 = TB[b];
    const int total = min(total0, BKCAP);
    const int base = bucketBase[b];
    for (int i = t; i < nchunks; i += 256) {
        ccum[i]   = cumMat[(size_t)i * NBK + b];
        cstart[i] = startMat[(size_t)i * NBK + b];
    }
    if (t < 128) hist[t] = 0;
    if (t == 0) ccum[nchunks] = total0;
    __syncthreads();
    for (int i = t; i < total; i += 256) {
        int lo = 0, hi = nchunks - 1;
        while (lo < hi) {
            int mid = (lo + hi + 1) >> 1;
            if (ccum[mid] <= i) lo = mid; else hi = mid - 1;
        }
        unsigned v = pairs1[(size_t)lo * CHUNK + cstart[lo] + (i - ccum[lo])];
        lp[i] = v;
        atomicAdd(&hist[v >> 17], 1);
    }
    __syncthreads();
    if (t < 128) sc[t] = hist[t];
    __syncthreads();
    #pragma unroll
    for (int o = 1; o < 128; o <<= 1) {
        int x = (t >= o && t < 128) ? sc[t - o] : 0;
        __syncthreads();
        if (t < 128) sc[t] += x;
        __syncthreads();
    }
    if (t < 128) {
        int excl = sc[t] - hist[t];
        foffs[t] = excl;
        int node = b * 128 + t;
        if (node < N) {
            rofs[node] = base + excl;
            dinv[node] = rsqrtf((float)hist[t] + 1.0f);   // +1 self-loop
        }
    }
    if (b == 0 && t == 255) rofs[N] = E;
    __syncthreads();
    for (int i = t; i < total; i += 256) {
        unsigned v = lp[i];
        int pos = atomicAdd(&foffs[v >> 17], 1);
        csrc[base + pos] = (int)(v & 0x1FFFFu);
    }
}

// ---- GEMM: G[row,:] = fp16((X[row,:] @ W) * dinv[row]), 64 cols ----
template<int K>
__global__ __launch_bounds__(256) void k_gemm(const float* __restrict__ X,
        const float* __restrict__ Wm, const float* __restrict__ dinv,
        __half* __restrict__ G, int nrows) {
    constexpr int BK = 32;
    constexpr int NCH = K / BK;
    constexpr int PITCH = 132;
    __shared__ float Xs[BK * PITCH];
    __shared__ float Ws[BK * 64];
    const int t = threadIdx.x;
    const int cg = t & 7;
    const int rg = t >> 3;
    const int brow = blockIdx.x * 128;

    float acc[4][8];
    #pragma unroll
    for (int r = 0; r < 4; ++r)
        #pragma unroll
        for (int c = 0; c < 8; ++c) acc[r][c] = 0.f;

    for (int ch = 0; ch < NCH; ++ch) {
        if (ch) __syncthreads();
        #pragma unroll
        for (int i = 0; i < 4; ++i) {
            int f = t + i * 256;
            int r = f >> 3, c4 = f & 7;
            int gr = brow + r;
            float4 v = make_float4(0.f, 0.f, 0.f, 0.f);
            if (gr < nrows)
                v = *(const float4*)(X + (size_t)gr * K + ch * BK + c4 * 4);
            Xs[(c4 * 4 + 0) * PITCH + r] = v.x;
            Xs[(c4 * 4 + 1) * PITCH + r] = v.y;
            Xs[(c4 * 4 + 2) * PITCH + r] = v.z;
            Xs[(c4 * 4 + 3) * PITCH + r] = v.w;
        }
        #pragma unroll
        for (int i = 0; i < 2; ++i) {
            int f = t + i * 256;
            int k = f >> 4, c4 = f & 15;
            *(float4*)(Ws + k * 64 + c4 * 4) =
                *(const float4*)(Wm + (size_t)(ch * BK + k) * 64 + c4 * 4);
        }
        __syncthreads();

        #pragma unroll
        for (int k = 0; k < BK; ++k) {
            float4 xa = *(const float4*)(Xs + k * PITCH + rg * 4);
            float4 w0 = *(const float4*)(Ws + k * 64 + cg * 8);
            float4 w1 = *(const float4*)(Ws + k * 64 + cg * 8 + 4);
#define FMA_ROW(r, xv) \
            acc[r][0] += (xv) * w0.x; acc[r][1] += (xv) * w0.y; \
            acc[r][2] += (xv) * w0.z; acc[r][3] += (xv) * w0.w; \
            acc[r][4] += (xv) * w1.x; acc[r][5] += (xv) * w1.y; \
            acc[r][6] += (xv) * w1.z; acc[r][7] += (xv) * w1.w;
            FMA_ROW(0, xa.x) FMA_ROW(1, xa.y) FMA_ROW(2, xa.z) FMA_ROW(3, xa.w)
#undef FMA_ROW
        }
    }
    #pragma unroll
    for (int r = 0; r < 4; ++r) {
        int gr = brow + rg * 4 + r;
        if (gr < nrows) {
            float dv = dinv[gr];
            __half2 h01 = __floats2half2_rn(acc[r][0] * dv, acc[r][1] * dv);
            __half2 h23 = __floats2half2_rn(acc[r][2] * dv, acc[r][3] * dv);
            __half2 h45 = __floats2half2_rn(acc[r][4] * dv, acc[r][5] * dv);
            __half2 h67 = __floats2half2_rn(acc[r][6] * dv, acc[r][7] * dv);
            uint4 pk;
            pk.x = *(unsigned*)&h01; pk.y = *(unsigned*)&h23;
            pk.z = *(unsigned*)&h45; pk.w = *(unsigned*)&h67;
            *(uint4*)(G + (size_t)gr * 64 + cg * 8) = pk;
        }
    }
}

// ---- Aggregate: H[d,:] = relu(dinv[d]*(G[d,:] + sum_{e in CSR[d]} G[src_e,:]) + b)
// One wave per node; 8 edge-slots x 8 lanes (uint4 = 16B = 8 fp16 features).
// Each lane loads its own csrc (8-lane broadcast) -> zero shuffles in the loop.
#define ACC8(A0, A1, V) { \
    float2 f0_ = __half22float2(*(const __half2*)&(V).x); \
    float2 f1_ = __half22float2(*(const __half2*)&(V).y); \
    float2 f2_ = __half22float2(*(const __half2*)&(V).z); \
    float2 f3_ = __half22float2(*(const __half2*)&(V).w); \
    (A0).x += f0_.x; (A0).y += f0_.y; (A0).z += f1_.x; (A0).w += f1_.y; \
    (A1).x += f2_.x; (A1).y += f2_.y; (A1).z += f3_.x; (A1).w += f3_.y; }

__global__ __launch_bounds__(256) void k_agg(const __half* __restrict__ G,
        const int* __restrict__ rofs, const int* __restrict__ csrc,
        const float* __restrict__ dinv, const float* __restrict__ bias,
        float* __restrict__ H, int nrows) {
    const int l = threadIdx.x & 63;
    const int g = l >> 3;                  // edge slot 0..7
    const int p = l & 7;                   // 16B chunk within row
    const int d = blockIdx.x * 4 + (threadIdx.x >> 6);
    if (d >= nrows) return;                // wave-uniform
    const int beg = rofs[d], end = rofs[d + 1];
    float4 a0 = make_float4(0.f, 0.f, 0.f, 0.f);
    float4 a1 = make_float4(0.f, 0.f, 0.f, 0.f);

    int e = beg + g;
    for (; e + 8 < end; e += 16) {         // 2 edges in flight per slot
        int s0 = csrc[e];
        int s1 = csrc[e + 8];
        uint4 v0 = *(const uint4*)(G + (size_t)s0 * 64 + p * 8);
        uint4 v1 = *(const uint4*)(G + (size_t)s1 * 64 + p * 8);
        ACC8(a0, a1, v0)
        ACC8(a0, a1, v1)
    }
    if (e < end) {
        int s = csrc[e];
        uint4 v = *(const uint4*)(G + (size_t)s * 64 + p * 8);
        ACC8(a0, a1, v)
    }
    // reduce across the 8 slots (xor lane bits 3,4,5)
    #pragma unroll
    for (int off = 8; off <= 32; off <<= 1) {
        a0.x += __shfl_xor(a0.x, off); a0.y += __shfl_xor(a0.y, off);
        a0.z += __shfl_xor(a0.z, off); a0.w += __shfl_xor(a0.w, off);
        a1.x += __shfl_xor(a1.x, off); a1.y += __shfl_xor(a1.y, off);
        a1.z += __shfl_xor(a1.z, off); a1.w += __shfl_xor(a1.w, off);
    }
    if (g == 0) {
        uint4 sv = *(const uint4*)(G + (size_t)d * 64 + p * 8);
        float2 s0 = __half22float2(*(const __half2*)&sv.x);
        float2 s1 = __half22float2(*(const __half2*)&sv.y);
        float2 s2 = __half22float2(*(const __half2*)&sv.z);
        float2 s3 = __half22float2(*(const __half2*)&sv.w);
        const float dv = dinv[d];
        const float4* B4 = (const float4*)bias;
        float4 b0 = B4[p * 2], b1 = B4[p * 2 + 1];
        float4 o0, o1;
        o0.x = fmaxf((a0.x + s0.x) * dv + b0.x, 0.f);
        o0.y = fmaxf((a0.y + s0.y) * dv + b0.y, 0.f);
        o0.z = fmaxf((a0.z + s1.x) * dv + b0.z, 0.f);
        o0.w = fmaxf((a0.w + s1.y) * dv + b0.w, 0.f);
        o1.x = fmaxf((a1.x + s2.x) * dv + b1.x, 0.f);
        o1.y = fmaxf((a1.y + s2.y) * dv + b1.y, 0.f);
        o1.z = fmaxf((a1.z + s3.x) * dv + b1.z, 0.f);
        o1.w = fmaxf((a1.w + s3.y) * dv + b1.w, 0.f);
        float4* H4 = (float4*)(H + (size_t)d * 64 + p * 8);
        H4[0] = o0; H4[1] = o1;
    }
}

// ---- Head: out[row,:] = log_softmax(H[row,:] @ W3 + b3), OUT=40 ----
// LDS-staged: coalesced H load -> padded LDS; per-thread row compute;
// output staged in LDS -> fully coalesced global write.
__global__ __launch_bounds__(256) void k_final(const float* __restrict__ H,
        const float* __restrict__ W3, const float* __restrict__ b3,
        float* __restrict__ out, int nrows) {
    constexpr int HP = 68;                 // H stage pitch (16B-aligned, bank-spread)
    constexpr int OP = 44;                 // out stage pitch
    __shared__ float wl[64 * 40];          // 10.24 KB
    __shared__ float bl[40];
    __shared__ float Hs[256 * HP];         // 69.6 KB (reused for out staging)
    const int t = threadIdx.x;
    for (int i = t; i < 640; i += 256)
        ((float4*)wl)[i] = ((const float4*)W3)[i];
    if (t < 40) bl[t] = b3[t];
    const int brow = blockIdx.x * 256;
    const int rows = min(256, nrows - brow);
    for (int i = t; i < rows * 16; i += 256) {       // coalesced H stage
        int r = i >> 4, c = i & 15;
        float4 v = ((const float4*)(H + (size_t)(brow + r) * 64))[c];
        *(float4*)&Hs[r * HP + c * 4] = v;
    }
    __syncthreads();

    float acc[40];
    float lse = 0.f;
    if (t < rows) {
        #pragma unroll
        for (int j = 0; j < 40; ++j) acc[j] = bl[j];
        #pragma unroll
        for (int k4 = 0; k4 < 16; ++k4) {
            float4 h4 = *(const float4*)&Hs[t * HP + k4 * 4];
            float hv[4] = {h4.x, h4.y, h4.z, h4.w};
            #pragma unroll
            for (int c = 0; c < 4; ++c) {
                const float4* wr = (const float4*)(wl + (k4 * 4 + c) * 40);
                #pragma unroll
                for (int j4 = 0; j4 < 10; ++j4) {
                    float4 wv = wr[j4];
                    acc[j4 * 4 + 0] += hv[c] * wv.x;
                    acc[j4 * 4 + 1] += hv[c] * wv.y;
                    acc[j4 * 4 + 2] += hv[c] * wv.z;
                    acc[j4 * 4 + 3] += hv[c] * wv.w;
                }
            }
        }
        float m = acc[0];
        #pragma unroll
        for (int j = 1; j < 40; ++j) m = fmaxf(m, acc[j]);
        float s = 0.f;
        #pragma unroll
        for (int j = 0; j < 40; ++j) s += expf(acc[j] - m);
        lse = m + logf(s);
    }
    __syncthreads();                       // all reads of Hs done
    float* Os = Hs;                        // reuse as out stage [256][OP]
    if (t < rows) {
        #pragma unroll
        for (int j4 = 0; j4 < 10; ++j4)
            *(float4*)&Os[t * OP + j4 * 4] =
                make_float4(acc[j4 * 4 + 0] - lse, acc[j4 * 4 + 1] - lse,
                            acc[j4 * 4 + 2] - lse, acc[j4 * 4 + 3] - lse);
    }
    __syncthreads();
    for (int i = t; i < rows * 40; i += 256) {       // coalesced writeout
        int r = i / 40, c = i - r * 40;
        out[(size_t)brow * 40 + i] = Os[r * OP + c];
    }
}

extern "C" void kernel_launch(void* const* d_in, const int* in_sizes, int n_in,
                              void* d_out, int out_size, void* d_ws, size_t ws_size,
                              hipStream_t stream) {
    const float* x  = (const float*)d_in[0];
    const int*   ei = (const int*)d_in[1];     // [2][E]: row0=src, row1=dst
    const float* W1 = (const float*)d_in[2];
    const float* b1 = (const float*)d_in[3];
    const float* W2 = (const float*)d_in[4];
    const float* b2 = (const float*)d_in[5];
    const float* W3 = (const float*)d_in[6];
    const float* b3 = (const float*)d_in[7];
    float* out = (float*)d_out;

    const int HID = in_sizes[3];            // 64
    const int IND = in_sizes[2] / HID;      // 256
    const int N   = in_sizes[0] / IND;      // 100000
    const int E   = in_sizes[1] / 2;        // 3200000
    (void)HID; (void)n_in; (void)out_size; (void)ws_size;

    const int NBK     = (N + 127) >> 7;             // 782
    const int nchunks = (E + CHUNK - 1) / CHUNK;    // 391

    char* ws = (char*)d_ws;
    size_t off = 0;
    auto alloc = [&](size_t bytes) -> char* {
        char* p = ws + off;
        off = (off + bytes + 255) & ~(size_t)255;
        return p;
    };
    size_t gbytes = (size_t)N * 64 * 2;             // fp16 G
    size_t p1bytes = (size_t)E * 4;                 // pairs1 overlay
    int*      cntMat     = (int*)     alloc((size_t)nchunks * NBK * 4);
    int*      startMat   = (int*)     alloc((size_t)nchunks * NBK * 4);
    int*      TB         = (int*)     alloc((size_t)NBK * 4);
    int*      bucketBase = (int*)     alloc(((size_t)NBK + 1) * 4);
    float*    dinv       = (float*)   alloc((size_t)N * 4);
    int*      rofs       = (int*)     alloc(((size_t)N + 1) * 4);
    int*      csrc       = (int*)     alloc((size_t)E * 4);
    __half*   g          = (__half*)  alloc(gbytes > p1bytes ? gbytes : p1bytes);
    float*    h          = (float*)   alloc((size_t)N * 64 * 4);
    unsigned* pairs1     = (unsigned*)g;    // overlay: dead before gemm1 writes g

    const int* esrc = ei;
    const int* edst = ei + E;
    const int gM = (N + 127) / 128;
    const int gN = (N + 255) / 256;

    p2_localsort<<<nchunks, 256, 0, stream>>>(esrc, edst, E, pairs1, cntMat, startMat, NBK);
    p3_colscan  <<<NBK, 256, 0, stream>>>(cntMat, TB, nchunks, NBK);
    p4_scan     <<<1, 256, 0, stream>>>(TB, bucketBase, NBK, E);
    p6_sortcsr  <<<NBK, 256, 0, stream>>>(pairs1, cntMat, startMat, TB, bucketBase,
                                          nchunks, NBK, csrc, rofs, dinv, N, E);

    k_gemm<256> <<<gM, 256, 0, stream>>>(x, W1, dinv, g, N);
    k_agg       <<<(N + 3) / 4, 256, 0, stream>>>(g, rofs, csrc, dinv, b1, h, N);
    k_gemm<64>  <<<gM, 256, 0, stream>>>(h, W2, dinv, g, N);
    k_agg       <<<(N + 3) / 4, 256, 0, stream>>>(g, rofs, csrc, dinv, b2, h, N);
    k_final     <<<gN, 256, 0, stream>>>(h, W3, b3, out, N);
}